// Round 10
// baseline (112.590 us; speedup 1.0000x reference)
//
#include <hip/hip_runtime.h>

#define Bn 8
#define Sn 2048
#define Cn 768
#define Hn 64
#define BS (Bn * Sn)

typedef __attribute__((ext_vector_type(8))) short bf16x8;
typedef __attribute__((ext_vector_type(4))) float f32x4;

__device__ __forceinline__ unsigned short f2bf(float x) {
  unsigned int u = __builtin_bit_cast(unsigned int, x);
  u += 0x7FFFu + ((u >> 16) & 1u);
  return (unsigned short)(u >> 16);
}

// async global->LDS DMA, 16B per lane; dest = wave-uniform base + lane*16 (linear)
__device__ __forceinline__ void gload_lds16(const void* g, void* l) {
  __builtin_amdgcn_global_load_lds(
      (const __attribute__((address_space(1))) unsigned int*)g,
      (__attribute__((address_space(3))) unsigned int*)l, 16, 0, 0);
}

// ---------------- kernel 0: W convert + transpose: W[c][h] f32 -> Wt[h][c] bf16 ----------------
__global__ __launch_bounds__(256) void wconv(const float* __restrict__ Wq,
                                             const float* __restrict__ Wk,
                                             const float* __restrict__ Wv,
                                             unsigned short* __restrict__ Wt) {
  int idx = blockIdx.x * 256 + threadIdx.x;      // 3*768*64 = 147456 total
  int mat = idx / (Cn * Hn);
  int rem = idx - mat * (Cn * Hn);
  int c = rem / Hn, h = rem - c * Hn;
  const float* W = (mat == 0) ? Wq : (mat == 1) ? Wk : Wv;
  Wt[mat * (Hn * Cn) + h * Cn + c] = f2bf(W[rem]);
}

// ---------------- kernel 0b: X stream-convert f32 -> bf16 (THE PROBE: m13 regime) ----------------
// grid-stride float4 -> ushort4, no LDS, no barriers, 2048 blocks x 256 threads.
// dur_us of this dispatch measures the achievable streaming rate on this data.
__global__ __launch_bounds__(256) void xconv(const float* __restrict__ src,
                                             unsigned short* __restrict__ dst, int n4) {
  int stride = gridDim.x * 256;
  for (int i = blockIdx.x * 256 + threadIdx.x; i < n4; i += stride) {
    float4 xv = *(const float4*)(src + (size_t)i * 4);
    ushort4 hv;
    hv.x = f2bf(xv.x); hv.y = f2bf(xv.y); hv.z = f2bf(xv.z); hv.w = f2bf(xv.w);
    *(ushort4*)(dst + (size_t)i * 4) = hv;
  }
}

// ---------------- kernel 1a: projection from bf16 X, DMA + counted vmcnt ----------------
// Chunk = 64 rows x 64 bf16 (8KB) + W 8KB = 4 DMA instrs/chunk. Double-buffer,
// vmcnt(4) steady (chunk c landed, c+1 in flight), drain only at last iter.
// LDS linear dest + source pre-swizzle: X slot sidx=(row<<3)|slot holds logical
// slot slot^(row&7); read logical s=ks*4+grp at linear slot s^(rloc&7) (<=2-way banks).
__global__ __launch_bounds__(256) void projb(const unsigned short* __restrict__ qx,
                                             const unsigned short* __restrict__ kx,
                                             const unsigned short* __restrict__ vx,
                                             const float* __restrict__ bq,
                                             const float* __restrict__ bk,
                                             const float* __restrict__ bv,
                                             const unsigned short* __restrict__ Wt,
                                             unsigned short* __restrict__ qi,
                                             unsigned short* __restrict__ ki,
                                             unsigned short* __restrict__ vi) {
  const int mat  = blockIdx.x >> 8;
  const int row0 = (blockIdx.x & 255) * 64;
  const unsigned short* X = (mat == 0) ? qx : (mat == 1) ? kx : vx;
  const float* bias = (mat == 0) ? bq : (mat == 1) ? bk : bv;
  unsigned short* Y = (mat == 0) ? qi : (mat == 1) ? ki : vi;
  const unsigned short* Wm = Wt + mat * (Hn * Cn);
  const float scale = (mat == 0) ? 0.03608439182435161f : 1.0f;  // 1/sqrt(768) folded into qi

  __shared__ __align__(16) unsigned short Xl[2][4096];   // 2 x 8KB
  __shared__ __align__(16) unsigned short Wl[2][4096];   // 2 x 8KB

  const int tid  = threadIdx.x;
  const int lane = tid & 63;
  const int w    = tid >> 6;
  const int col  = lane & 15;
  const int grp  = lane >> 4;

  // pre-swizzled per-thread global sources (chunk 0)
  const unsigned short* xsrc[2];
#pragma unroll
  for (int j = 0; j < 2; ++j) {
    int sidx = j * 256 + tid;
    int xr   = sidx >> 3;
    int xs   = (sidx & 7) ^ (xr & 7);
    xsrc[j]  = X + (size_t)(row0 + xr) * Cn + xs * 8;
  }
  const unsigned short* wsrc[2];
#pragma unroll
  for (int j = 0; j < 2; ++j) {
    int sidx = j * 256 + tid;
    int h    = sidx >> 3;
    int pd   = (sidx & 7) ^ (h & 7);
    wsrc[j]  = Wm + (size_t)h * Cn + pd * 8;
  }

  // prologue: chunk 0 -> buf0, chunk 1 -> buf1 (8 DMAs outstanding)
#pragma unroll
  for (int j = 0; j < 2; ++j) gload_lds16(xsrc[j], &Xl[0][(j * 256 + w * 64) * 8]);
#pragma unroll
  for (int j = 0; j < 2; ++j) gload_lds16(wsrc[j], &Wl[0][(j * 256 + w * 64) * 8]);
#pragma unroll
  for (int j = 0; j < 2; ++j) gload_lds16(xsrc[j] + 64, &Xl[1][(j * 256 + w * 64) * 8]);
#pragma unroll
  for (int j = 0; j < 2; ++j) gload_lds16(wsrc[j] + 64, &Wl[1][(j * 256 + w * 64) * 8]);

  f32x4 acc[4] = {};
  const int rloc = w * 16 + col;

#pragma unroll
  for (int c = 0; c < 12; ++c) {
    const int buf = c & 1;
    if (c == 11) {
      asm volatile("s_waitcnt vmcnt(0)" ::: "memory");
    } else {
      asm volatile("s_waitcnt vmcnt(4)" ::: "memory");
    }
    __builtin_amdgcn_s_barrier();
    __builtin_amdgcn_sched_barrier(0);
#pragma unroll
    for (int ks = 0; ks < 2; ++ks) {
      const int s = ks * 4 + grp;
      bf16x8 av = *(const bf16x8*)&Xl[buf][(rloc * 8 + (s ^ (rloc & 7))) * 8];
#pragma unroll
      for (int nf = 0; nf < 4; ++nf) {
        int h = nf * 16 + col;
        bf16x8 bfr = *(const bf16x8*)&Wl[buf][(h * 8 + (s ^ (h & 7))) * 8];
        acc[nf] = __builtin_amdgcn_mfma_f32_16x16x32_bf16(av, bfr, acc[nf], 0, 0, 0);
      }
    }
    __builtin_amdgcn_sched_barrier(0);
    __builtin_amdgcn_s_barrier();    // all waves done reading this buf
    __builtin_amdgcn_sched_barrier(0);
    if (c < 10) {                    // refill with chunk c+2; stays in flight
#pragma unroll
      for (int j = 0; j < 2; ++j)
        gload_lds16(xsrc[j] + (c + 2) * 64, &Xl[buf][(j * 256 + w * 64) * 8]);
#pragma unroll
      for (int j = 0; j < 2; ++j)
        gload_lds16(wsrc[j] + (c + 2) * 64, &Wl[buf][(j * 256 + w * 64) * 8]);
    }
  }

#pragma unroll
  for (int nf = 0; nf < 4; ++nf) {
    int h = nf * 16 + col;
    float bb = bias[h];
#pragma unroll
    for (int r2 = 0; r2 < 4; ++r2) {
      int row = row0 + w * 16 + grp * 4 + r2;
      Y[(size_t)row * Hn + h] = f2bf((acc[nf][r2] + bb) * scale);
    }
  }
}

// ---------------- kernel 1b: fallback f32-X projection (R9, verified) ----------------
__global__ __launch_bounds__(256) void proj(const float* __restrict__ q,
                                            const float* __restrict__ k,
                                            const float* __restrict__ v,
                                            const float* __restrict__ bq,
                                            const float* __restrict__ bk,
                                            const float* __restrict__ bv,
                                            const unsigned short* __restrict__ Wt,
                                            unsigned short* __restrict__ qi,
                                            unsigned short* __restrict__ ki,
                                            unsigned short* __restrict__ vi) {
  const int mat  = blockIdx.x >> 8;
  const int row0 = (blockIdx.x & 255) * 64;
  const float* X    = (mat == 0) ? q  : (mat == 1) ? k  : v;
  const float* bias = (mat == 0) ? bq : (mat == 1) ? bk : bv;
  unsigned short* Y = (mat == 0) ? qi : (mat == 1) ? ki : vi;
  const unsigned short* Wm = Wt + mat * (Hn * Cn);
  const float scale = (mat == 0) ? 0.03608439182435161f : 1.0f;

  __shared__ __align__(16) float          Xf[2][4096];
  __shared__ __align__(16) unsigned short Wl[2][4096];

  const int tid  = threadIdx.x;
  const int lane = tid & 63;
  const int w    = tid >> 6;
  const int col  = lane & 15;
  const int grp  = lane >> 4;

  const float* xsrc[4];
#pragma unroll
  for (int j = 0; j < 4; ++j) {
    int sidx = j * 256 + tid;
    int row  = sidx >> 4;
    int cf4  = (sidx & 15) ^ (row & 15);
    xsrc[j]  = X + (size_t)(row0 + row) * Cn + cf4 * 4;
  }
  const unsigned short* wsrc[2];
#pragma unroll
  for (int j = 0; j < 2; ++j) {
    int sidx = j * 256 + tid;
    int h    = sidx >> 3;
    int pd   = (sidx & 7) ^ (h & 7);
    wsrc[j]  = Wm + (size_t)h * Cn + pd * 8;
  }

#pragma unroll
  for (int j = 0; j < 4; ++j) gload_lds16(xsrc[j], &Xf[0][(j * 256 + w * 64) * 4]);
#pragma unroll
  for (int j = 0; j < 2; ++j) gload_lds16(wsrc[j], &Wl[0][(j * 256 + w * 64) * 8]);
#pragma unroll
  for (int j = 0; j < 4; ++j) gload_lds16(xsrc[j] + 64, &Xf[1][(j * 256 + w * 64) * 4]);
#pragma unroll
  for (int j = 0; j < 2; ++j) gload_lds16(wsrc[j] + 64, &Wl[1][(j * 256 + w * 64) * 8]);

  f32x4 acc[4] = {};
  const int rloc = w * 16 + col;

#pragma unroll
  for (int c = 0; c < 12; ++c) {
    const int buf = c & 1;
    if (c == 11) {
      asm volatile("s_waitcnt vmcnt(0)" ::: "memory");
    } else {
      asm volatile("s_waitcnt vmcnt(6)" ::: "memory");
    }
    __builtin_amdgcn_s_barrier();
    __builtin_amdgcn_sched_barrier(0);
#pragma unroll
    for (int ks = 0; ks < 2; ++ks) {
      const int cf0 = ks * 8 + grp * 2;
      float4 a0 = *(const float4*)&Xf[buf][(rloc * 16 + (cf0 ^ col)) * 4];
      float4 a1 = *(const float4*)&Xf[buf][(rloc * 16 + ((cf0 + 1) ^ col)) * 4];
      bf16x8 av;
      av[0] = (short)f2bf(a0.x); av[1] = (short)f2bf(a0.y);
      av[2] = (short)f2bf(a0.z); av[3] = (short)f2bf(a0.w);
      av[4] = (short)f2bf(a1.x); av[5] = (short)f2bf(a1.y);
      av[6] = (short)f2bf(a1.z); av[7] = (short)f2bf(a1.w);
      const int p = ks * 4 + grp;
#pragma unroll
      for (int nf = 0; nf < 4; ++nf) {
        int h = nf * 16 + col;
        bf16x8 bfr = *(const bf16x8*)&Wl[buf][(h * 8 + (p ^ (h & 7))) * 8];
        acc[nf] = __builtin_amdgcn_mfma_f32_16x16x32_bf16(av, bfr, acc[nf], 0, 0, 0);
      }
    }
    __builtin_amdgcn_sched_barrier(0);
    __builtin_amdgcn_s_barrier();
    __builtin_amdgcn_sched_barrier(0);
    if (c < 10) {
#pragma unroll
      for (int j = 0; j < 4; ++j)
        gload_lds16(xsrc[j] + (c + 2) * 64, &Xf[buf][(j * 256 + w * 64) * 4]);
#pragma unroll
      for (int j = 0; j < 2; ++j)
        gload_lds16(wsrc[j] + (c + 2) * 64, &Wl[buf][(j * 256 + w * 64) * 8]);
    }
  }

#pragma unroll
  for (int nf = 0; nf < 4; ++nf) {
    int h = nf * 16 + col;
    float bb = bias[h];
#pragma unroll
    for (int r2 = 0; r2 < 4; ++r2) {
      int row = row0 + w * 16 + grp * 4 + r2;
      Y[(size_t)row * Hn + h] = f2bf((acc[nf][r2] + bb) * scale);
    }
  }
}

// ---------------- kernel 2: flash attention, optional KV split ----------------
template <int SPLIT>
__global__ __launch_bounds__(256) void attn(const unsigned short* __restrict__ qi,
                                            const unsigned short* __restrict__ ki,
                                            const unsigned short* __restrict__ vi,
                                            float* __restrict__ pacc,
                                            float* __restrict__ pm,
                                            float* __restrict__ pl,
                                            float* __restrict__ out,
                                            int tpb) {
  const int bq    = blockIdx.x & 255;
  const int split = blockIdx.x >> 8;
  const int b  = bq >> 5;
  const int s0 = (bq & 31) * 64;
  const int t0 = split * tpb;
  const unsigned short* Qb = qi + ((size_t)b * Sn + s0) * Hn;
  const unsigned short* Kb = ki + (size_t)b * Sn * Hn;
  const unsigned short* Vb = vi + (size_t)b * Sn * Hn;

  __shared__ __align__(16) unsigned char Ks[64 * 128];
  __shared__ __align__(16) unsigned char Vt[64 * 128];
  __shared__ __align__(16) unsigned char Ps[4 * 16 * 128];

  const int tid  = threadIdx.x;
  const int lane = tid & 63;
  const int w    = tid >> 6;
  const int col  = lane & 15;
  const int grp  = lane >> 4;

  bf16x8 qa[2];
#pragma unroll
  for (int ks2 = 0; ks2 < 2; ++ks2)
    qa[ks2] = *(const bf16x8*)(Qb + (size_t)(w * 16 + col) * Hn + ks2 * 32 + grp * 8);

  f32x4 acc[4] = {};
  float m[4], l[4];
#pragma unroll
  for (int r = 0; r < 4; ++r) { m[r] = -1e30f; l[r] = 0.0f; }

  for (int t = t0; t < t0 + tpb; ++t) {
    const unsigned short* Kt = Kb + t * 64 * Hn;
    const unsigned short* Vg = Vb + t * 64 * Hn;
    __syncthreads();
    {
      int kr = tid >> 2, p = tid & 3;
      const uint4* src = (const uint4*)(Kt + kr * Hn);
      uint4 a  = src[p * 2];
      uint4 b2 = src[p * 2 + 1];
      *(uint4*)(Ks + kr * 128 + ((p * 32) ^ ((kr & 7) << 4)))        = a;
      *(uint4*)(Ks + kr * 128 + (((p * 32) + 16) ^ ((kr & 7) << 4))) = b2;
    }
    {
      int kp = tid >> 3;
      int dg = tid & 7;
      uint4 v0 = *(const uint4*)(Vg + (2 * kp) * Hn + dg * 8);
      uint4 v1 = *(const uint4*)(Vg + (2 * kp + 1) * Hn + dg * 8);
      const unsigned short* a0 = (const unsigned short*)&v0;
      const unsigned short* a1 = (const unsigned short*)&v1;
#pragma unroll
      for (int j0 = 0; j0 < 8; ++j0) {
        int j = (j0 + dg) & 7;
        int d = dg * 8 + j;
        unsigned int pk = (unsigned int)a0[j] | ((unsigned int)a1[j] << 16);
        *(unsigned int*)(Vt + d * 128 + ((4 * kp) ^ ((d & 7) << 4))) = pk;
      }
    }
    __syncthreads();
    f32x4 sf[4] = {};
#pragma unroll
    for (int ks2 = 0; ks2 < 2; ++ks2) {
#pragma unroll
      for (int nf = 0; nf < 4; ++nf) {
        int kr = nf * 16 + col;
        bf16x8 bfr = *(const bf16x8*)(Ks + kr * 128 + ((ks2 * 64 + grp * 16) ^ ((kr & 7) << 4)));
        sf[nf] = __builtin_amdgcn_mfma_f32_16x16x32_bf16(qa[ks2], bfr, sf[nf], 0, 0, 0);
      }
    }
    float mn[4], fs[4];
#pragma unroll
    for (int r = 0; r < 4; ++r) {
      float mx = fmaxf(fmaxf(sf[0][r], sf[1][r]), fmaxf(sf[2][r], sf[3][r]));
#pragma unroll
      for (int off = 1; off < 16; off <<= 1)
        mx = fmaxf(mx, __shfl_xor(mx, off, 64));
      mn[r] = fmaxf(m[r], mx);
      fs[r] = __expf(m[r] - mn[r]);
      m[r]  = mn[r];
    }
#pragma unroll
    for (int nf = 0; nf < 4; ++nf)
#pragma unroll
      for (int r = 0; r < 4; ++r)
        sf[nf][r] = __expf(sf[nf][r] - mn[r]);
#pragma unroll
    for (int r = 0; r < 4; ++r) {
      float sm = sf[0][r] + sf[1][r] + sf[2][r] + sf[3][r];
#pragma unroll
      for (int off = 1; off < 16; off <<= 1)
        sm += __shfl_xor(sm, off, 64);
      l[r] = l[r] * fs[r] + sm;
    }
#pragma unroll
    for (int nf = 0; nf < 4; ++nf) {
#pragma unroll
      for (int r = 0; r < 4; ++r) {
        acc[nf][r] *= fs[r];
        int prow = grp * 4 + r;
        int key  = nf * 16 + col;
        *(unsigned short*)(Ps + w * 2048 + prow * 128 + ((key * 2) ^ ((prow & 7) << 4))) =
            f2bf(sf[nf][r]);
      }
    }
#pragma unroll
    for (int kk = 0; kk < 2; ++kk) {
      bf16x8 pa = *(const bf16x8*)(Ps + w * 2048 + col * 128 +
                                   ((kk * 64 + grp * 16) ^ ((col & 7) << 4)));
#pragma unroll
      for (int nf = 0; nf < 4; ++nf) {
        int dr = nf * 16 + col;
        bf16x8 bv = *(const bf16x8*)(Vt + dr * 128 + ((kk * 64 + grp * 16) ^ ((dr & 7) << 4)));
        acc[nf] = __builtin_amdgcn_mfma_f32_16x16x32_bf16(pa, bv, acc[nf], 0, 0, 0);
      }
    }
  }
  if (SPLIT) {
    const size_t sb = (size_t)split * BS + (size_t)b * Sn;
#pragma unroll
    for (int nf = 0; nf < 4; ++nf) {
#pragma unroll
      for (int r = 0; r < 4; ++r) {
        int row = s0 + w * 16 + grp * 4 + r;
        pacc[(sb + row) * Hn + nf * 16 + col] = acc[nf][r];
      }
    }
    if (col == 0) {
#pragma unroll
      for (int r = 0; r < 4; ++r) {
        int row = s0 + w * 16 + grp * 4 + r;
        pm[sb + row] = m[r];
        pl[sb + row] = l[r];
      }
    }
  } else {
#pragma unroll
    for (int nf = 0; nf < 4; ++nf) {
#pragma unroll
      for (int r = 0; r < 4; ++r) {
        int row = s0 + w * 16 + grp * 4 + r;
        out[((size_t)b * Sn + row) * Hn + nf * 16 + col] = acc[nf][r] / l[r];
      }
    }
  }
}

// ---------------- kernel 3: combine attn split partials ----------------
__global__ __launch_bounds__(256) void combine(const float* __restrict__ pacc,
                                               const float* __restrict__ pm,
                                               const float* __restrict__ pl,
                                               float* __restrict__ out,
                                               int nsplit) {
  int gid = blockIdx.x * 256 + threadIdx.x;
  int gr  = gid >> 4;
  int dq  = (gid & 15) * 4;
  float M = -1e30f;
  for (int s = 0; s < nsplit; ++s) M = fmaxf(M, pm[(size_t)s * BS + gr]);
  float L = 0.0f;
  float4 o = make_float4(0.f, 0.f, 0.f, 0.f);
  for (int s = 0; s < nsplit; ++s) {
    float wgt = __expf(pm[(size_t)s * BS + gr] - M);
    L += pl[(size_t)s * BS + gr] * wgt;
    float4 p = *(const float4*)(pacc + ((size_t)s * BS + gr) * Hn + dq);
    o.x += p.x * wgt; o.y += p.y * wgt; o.z += p.z * wgt; o.w += p.w * wgt;
  }
  float inv = 1.0f / L;
  float4 r = make_float4(o.x * inv, o.y * inv, o.z * inv, o.w * inv);
  *(float4*)(out + (size_t)gr * Hn + dq) = r;
}

extern "C" void kernel_launch(void* const* d_in, const int* in_sizes, int n_in,
                              void* d_out, int out_size, void* d_ws, size_t ws_size,
                              hipStream_t stream) {
  const float* q  = (const float*)d_in[0];
  const float* k  = (const float*)d_in[1];
  const float* v  = (const float*)d_in[2];
  const float* Wq = (const float*)d_in[3];
  const float* bq = (const float*)d_in[4];
  const float* Wk = (const float*)d_in[5];
  const float* bk = (const float*)d_in[6];
  const float* Wv = (const float*)d_in[7];
  const float* bv = (const float*)d_in[8];
  float* out = (float*)d_out;

  unsigned short* Wt = (unsigned short*)d_ws;            // [3][64][768] bf16
  unsigned short* qi = Wt + 3 * Hn * Cn;
  unsigned short* ki = qi + (size_t)BS * Hn;
  unsigned short* vi = ki + (size_t)BS * Hn;
  unsigned short* scratch = vi + (size_t)BS * Hn;        // shared: bf16-X, then attn partials

  const size_t base_bytes = (size_t)(3 * Hn * Cn + 3 * (size_t)BS * Hn) * 2;
  const size_t avail = (ws_size > base_bytes) ? ws_size - base_bytes : 0;

  const size_t xe = (size_t)BS * Cn;           // elems per X tensor
  const size_t xconv_bytes = 3 * xe * 2;       // 75.5 MB
  bool use_xc = (avail >= xconv_bytes);

  int nsplit = 4;
  while (nsplit > 1 &&
         (size_t)nsplit * ((size_t)BS * Hn * 4 + 2 * (size_t)BS * 4) > avail)
    nsplit >>= 1;
  bool direct = ((size_t)nsplit * ((size_t)BS * Hn * 4 + 2 * (size_t)BS * 4) > avail);

  unsigned short* qx = scratch;                // bf16 X (dead after projb)
  unsigned short* kx = qx + xe;
  unsigned short* vx = kx + xe;
  float* pacc = (float*)scratch;               // attn partials overlap bf16-X region
  float* pm   = pacc + (size_t)nsplit * BS * Hn;
  float* pl   = pm + (size_t)nsplit * BS;

  wconv<<<dim3((3 * Cn * Hn) / 256), dim3(256), 0, stream>>>(Wq, Wk, Wv, Wt);
  if (use_xc) {
    const int n4 = (int)(xe / 4);
    xconv<<<dim3(2048), dim3(256), 0, stream>>>(q, qx, n4);
    xconv<<<dim3(2048), dim3(256), 0, stream>>>(k, kx, n4);
    xconv<<<dim3(2048), dim3(256), 0, stream>>>(v, vx, n4);
    projb<<<dim3(768), dim3(256), 0, stream>>>(qx, kx, vx, bq, bk, bv, Wt, qi, ki, vi);
  } else {
    proj<<<dim3(768), dim3(256), 0, stream>>>(q, k, v, bq, bk, bv, Wt, qi, ki, vi);
  }
  if (direct) {
    attn<0><<<dim3(256), dim3(256), 0, stream>>>(qi, ki, vi, nullptr, nullptr, nullptr, out, 32);
  } else {
    attn<1><<<dim3(256 * nsplit), dim3(256), 0, stream>>>(qi, ki, vi, pacc, pm, pl, nullptr,
                                                          32 / nsplit);
    combine<<<dim3(BS * 16 / 256), dim3(256), 0, stream>>>(pacc, pm, pl, out, nsplit);
  }
}

// Round 11
// 112.159 us; speedup vs baseline: 1.0038x; 1.0038x over previous
//
#include <hip/hip_runtime.h>

#define Bn 8
#define Sn 2048
#define Cn 768
#define Hn 64
#define BS (Bn * Sn)

typedef __attribute__((ext_vector_type(8))) short bf16x8;
typedef __attribute__((ext_vector_type(4))) float f32x4;

__device__ __forceinline__ unsigned short f2bf(float x) {
  unsigned int u = __builtin_bit_cast(unsigned int, x);
  u += 0x7FFFu + ((u >> 16) & 1u);
  return (unsigned short)(u >> 16);
}

// ---------------- kernel 0: W convert + transpose: W[c][h] f32 -> Wt[h][c] bf16 ----------------
__global__ __launch_bounds__(256) void wconv(const float* __restrict__ Wq,
                                             const float* __restrict__ Wk,
                                             const float* __restrict__ Wv,
                                             unsigned short* __restrict__ Wt) {
  int idx = blockIdx.x * 256 + threadIdx.x;      // 3*768*64 = 147456 total
  int mat = idx / (Cn * Hn);
  int rem = idx - mat * (Cn * Hn);
  int c = rem / Hn, h = rem - c * Hn;
  const float* W = (mat == 0) ? Wq : (mat == 1) ? Wk : Wv;
  Wt[mat * (Hn * Cn) + h * Cn + c] = f2bf(W[rem]);
}

// ---------------- kernel 1: projection, register-direct (no LDS, no barriers) ----------------
// Block = 4 waves x 16 rows = 64 rows, 64 cols, K=768. Per lane: A-slice 32B contiguous
// f32 from X, 8 W-fragments 16B from global Wt (L2-hot broadcast). Depth-1 reg prefetch,
// in-reg f32->bf16 cvt, 8 MFMA/chunk. 12 independent barrier-free waves per CU (xconv's
// regime + MFMA). 256-thread blocks, no tight launch_bounds -> no scratch spill (R3's bug).
__global__ __launch_bounds__(256, 1) void proj(const float* __restrict__ q,
                                               const float* __restrict__ k,
                                               const float* __restrict__ v,
                                               const float* __restrict__ bq,
                                               const float* __restrict__ bk,
                                               const float* __restrict__ bv,
                                               const unsigned short* __restrict__ Wt,
                                               unsigned short* __restrict__ qi,
                                               unsigned short* __restrict__ ki,
                                               unsigned short* __restrict__ vi) {
  const int mat  = blockIdx.x >> 8;
  const int row0 = (blockIdx.x & 255) * 64;
  const float* X    = (mat == 0) ? q  : (mat == 1) ? k  : v;
  const float* bias = (mat == 0) ? bq : (mat == 1) ? bk : bv;
  unsigned short* Y = (mat == 0) ? qi : (mat == 1) ? ki : vi;
  const unsigned short* Wm = Wt + mat * (Hn * Cn);
  const float scale = (mat == 0) ? 0.03608439182435161f : 1.0f;  // 1/sqrt(768) folded into qi

  const int tid  = threadIdx.x;
  const int lane = tid & 63;
  const int w    = tid >> 6;
  const int col  = lane & 15;
  const int grp  = lane >> 4;

  // per-lane operand base pointers
  const float* Xr = X + (size_t)(row0 + w * 16 + col) * Cn + grp * 8;   // A: row, k=grp*8
  const unsigned short* Wl = Wm + (size_t)col * Cn + grp * 8;           // B: h=col (+nf*16)

  // double-buffered operand registers ((c&1) static after full unroll)
  float4 xa[2][4];    // [buf][ks*2+piece] : A slice, 2 ks x 8 f32
  bf16x8 wb[2][8];    // [buf][ks*4+nf]    : 8 W fragments

#pragma unroll
  for (int ks = 0; ks < 2; ++ks) {
    xa[0][ks * 2]     = *(const float4*)(Xr + ks * 32);
    xa[0][ks * 2 + 1] = *(const float4*)(Xr + ks * 32 + 4);
#pragma unroll
    for (int nf = 0; nf < 4; ++nf)
      wb[0][ks * 4 + nf] = *(const bf16x8*)(Wl + (size_t)(nf * 16) * Cn + ks * 32);
  }

  f32x4 acc[4] = {};

#pragma unroll
  for (int c = 0; c < 12; ++c) {
    const int cur = c & 1;
    const int nxt = cur ^ 1;
    // depth-1 prefetch: issue chunk c+1 loads first (fly under this chunk's cvt+MFMA)
    if (c < 11) {
#pragma unroll
      for (int ks = 0; ks < 2; ++ks) {
        xa[nxt][ks * 2]     = *(const float4*)(Xr + (c + 1) * 64 + ks * 32);
        xa[nxt][ks * 2 + 1] = *(const float4*)(Xr + (c + 1) * 64 + ks * 32 + 4);
#pragma unroll
        for (int nf = 0; nf < 4; ++nf)
          wb[nxt][ks * 4 + nf] =
              *(const bf16x8*)(Wl + (size_t)(nf * 16) * Cn + (c + 1) * 64 + ks * 32);
      }
    }
    // compute chunk c
#pragma unroll
    for (int ks = 0; ks < 2; ++ks) {
      const float4 p0 = xa[cur][ks * 2], p1 = xa[cur][ks * 2 + 1];
      bf16x8 av;
      av[0] = (short)f2bf(p0.x); av[1] = (short)f2bf(p0.y);
      av[2] = (short)f2bf(p0.z); av[3] = (short)f2bf(p0.w);
      av[4] = (short)f2bf(p1.x); av[5] = (short)f2bf(p1.y);
      av[6] = (short)f2bf(p1.z); av[7] = (short)f2bf(p1.w);
#pragma unroll
      for (int nf = 0; nf < 4; ++nf)
        acc[nf] = __builtin_amdgcn_mfma_f32_16x16x32_bf16(av, wb[cur][ks * 4 + nf], acc[nf],
                                                          0, 0, 0);
    }
  }

  // epilogue: D layout col = lane&15, row = grp*4 + reg
#pragma unroll
  for (int nf = 0; nf < 4; ++nf) {
    int h = nf * 16 + col;
    float bb = bias[h];
#pragma unroll
    for (int r2 = 0; r2 < 4; ++r2) {
      int row = row0 + w * 16 + grp * 4 + r2;
      Y[(size_t)row * Hn + h] = f2bf((acc[nf][r2] + bb) * scale);
    }
  }
}

// ---------------- kernel 2: flash attention, optional KV split ----------------
template <int SPLIT>
__global__ __launch_bounds__(256) void attn(const unsigned short* __restrict__ qi,
                                            const unsigned short* __restrict__ ki,
                                            const unsigned short* __restrict__ vi,
                                            float* __restrict__ pacc,
                                            float* __restrict__ pm,
                                            float* __restrict__ pl,
                                            float* __restrict__ out,
                                            int tpb) {
  const int bq    = blockIdx.x & 255;
  const int split = blockIdx.x >> 8;
  const int b  = bq >> 5;
  const int s0 = (bq & 31) * 64;
  const int t0 = split * tpb;
  const unsigned short* Qb = qi + ((size_t)b * Sn + s0) * Hn;
  const unsigned short* Kb = ki + (size_t)b * Sn * Hn;
  const unsigned short* Vb = vi + (size_t)b * Sn * Hn;

  __shared__ __align__(16) unsigned char Ks[64 * 128];
  __shared__ __align__(16) unsigned char Vt[64 * 128];
  __shared__ __align__(16) unsigned char Ps[4 * 16 * 128];

  const int tid  = threadIdx.x;
  const int lane = tid & 63;
  const int w    = tid >> 6;
  const int col  = lane & 15;
  const int grp  = lane >> 4;

  bf16x8 qa[2];
#pragma unroll
  for (int ks2 = 0; ks2 < 2; ++ks2)
    qa[ks2] = *(const bf16x8*)(Qb + (size_t)(w * 16 + col) * Hn + ks2 * 32 + grp * 8);

  f32x4 acc[4] = {};
  float m[4], l[4];
#pragma unroll
  for (int r = 0; r < 4; ++r) { m[r] = -1e30f; l[r] = 0.0f; }

  for (int t = t0; t < t0 + tpb; ++t) {
    const unsigned short* Kt = Kb + t * 64 * Hn;
    const unsigned short* Vg = Vb + t * 64 * Hn;
    __syncthreads();
    {
      int kr = tid >> 2, p = tid & 3;
      const uint4* src = (const uint4*)(Kt + kr * Hn);
      uint4 a  = src[p * 2];
      uint4 b2 = src[p * 2 + 1];
      *(uint4*)(Ks + kr * 128 + ((p * 32) ^ ((kr & 7) << 4)))        = a;
      *(uint4*)(Ks + kr * 128 + (((p * 32) + 16) ^ ((kr & 7) << 4))) = b2;
    }
    {
      int kp = tid >> 3;
      int dg = tid & 7;
      uint4 v0 = *(const uint4*)(Vg + (2 * kp) * Hn + dg * 8);
      uint4 v1 = *(const uint4*)(Vg + (2 * kp + 1) * Hn + dg * 8);
      const unsigned short* a0 = (const unsigned short*)&v0;
      const unsigned short* a1 = (const unsigned short*)&v1;
#pragma unroll
      for (int j0 = 0; j0 < 8; ++j0) {
        int j = (j0 + dg) & 7;
        int d = dg * 8 + j;
        unsigned int pk = (unsigned int)a0[j] | ((unsigned int)a1[j] << 16);
        *(unsigned int*)(Vt + d * 128 + ((4 * kp) ^ ((d & 7) << 4))) = pk;
      }
    }
    __syncthreads();
    f32x4 sf[4] = {};
#pragma unroll
    for (int ks2 = 0; ks2 < 2; ++ks2) {
#pragma unroll
      for (int nf = 0; nf < 4; ++nf) {
        int kr = nf * 16 + col;
        bf16x8 bfr = *(const bf16x8*)(Ks + kr * 128 + ((ks2 * 64 + grp * 16) ^ ((kr & 7) << 4)));
        sf[nf] = __builtin_amdgcn_mfma_f32_16x16x32_bf16(qa[ks2], bfr, sf[nf], 0, 0, 0);
      }
    }
    float mn[4], fs[4];
#pragma unroll
    for (int r = 0; r < 4; ++r) {
      float mx = fmaxf(fmaxf(sf[0][r], sf[1][r]), fmaxf(sf[2][r], sf[3][r]));
#pragma unroll
      for (int off = 1; off < 16; off <<= 1)
        mx = fmaxf(mx, __shfl_xor(mx, off, 64));
      mn[r] = fmaxf(m[r], mx);
      fs[r] = __expf(m[r] - mn[r]);
      m[r]  = mn[r];
    }
#pragma unroll
    for (int nf = 0; nf < 4; ++nf)
#pragma unroll
      for (int r = 0; r < 4; ++r)
        sf[nf][r] = __expf(sf[nf][r] - mn[r]);
#pragma unroll
    for (int r = 0; r < 4; ++r) {
      float sm = sf[0][r] + sf[1][r] + sf[2][r] + sf[3][r];
#pragma unroll
      for (int off = 1; off < 16; off <<= 1)
        sm += __shfl_xor(sm, off, 64);
      l[r] = l[r] * fs[r] + sm;
    }
#pragma unroll
    for (int nf = 0; nf < 4; ++nf) {
#pragma unroll
      for (int r = 0; r < 4; ++r) {
        acc[nf][r] *= fs[r];
        int prow = grp * 4 + r;
        int key  = nf * 16 + col;
        *(unsigned short*)(Ps + w * 2048 + prow * 128 + ((key * 2) ^ ((prow & 7) << 4))) =
            f2bf(sf[nf][r]);
      }
    }
#pragma unroll
    for (int kk = 0; kk < 2; ++kk) {
      bf16x8 pa = *(const bf16x8*)(Ps + w * 2048 + col * 128 +
                                   ((kk * 64 + grp * 16) ^ ((col & 7) << 4)));
#pragma unroll
      for (int nf = 0; nf < 4; ++nf) {
        int dr = nf * 16 + col;
        bf16x8 bv = *(const bf16x8*)(Vt + dr * 128 + ((kk * 64 + grp * 16) ^ ((dr & 7) << 4)));
        acc[nf] = __builtin_amdgcn_mfma_f32_16x16x32_bf16(pa, bv, acc[nf], 0, 0, 0);
      }
    }
  }
  if (SPLIT) {
    const size_t sb = (size_t)split * BS + (size_t)b * Sn;
#pragma unroll
    for (int nf = 0; nf < 4; ++nf) {
#pragma unroll
      for (int r = 0; r < 4; ++r) {
        int row = s0 + w * 16 + grp * 4 + r;
        pacc[(sb + row) * Hn + nf * 16 + col] = acc[nf][r];
      }
    }
    if (col == 0) {
#pragma unroll
      for (int r = 0; r < 4; ++r) {
        int row = s0 + w * 16 + grp * 4 + r;
        pm[sb + row] = m[r];
        pl[sb + row] = l[r];
      }
    }
  } else {
#pragma unroll
    for (int nf = 0; nf < 4; ++nf) {
#pragma unroll
      for (int r = 0; r < 4; ++r) {
        int row = s0 + w * 16 + grp * 4 + r;
        out[((size_t)b * Sn + row) * Hn + nf * 16 + col] = acc[nf][r] / l[r];
      }
    }
  }
}

// ---------------- kernel 3: combine attn split partials ----------------
__global__ __launch_bounds__(256) void combine(const float* __restrict__ pacc,
                                               const float* __restrict__ pm,
                                               const float* __restrict__ pl,
                                               float* __restrict__ out,
                                               int nsplit) {
  int gid = blockIdx.x * 256 + threadIdx.x;
  int gr  = gid >> 4;
  int dq  = (gid & 15) * 4;
  float M = -1e30f;
  for (int s = 0; s < nsplit; ++s) M = fmaxf(M, pm[(size_t)s * BS + gr]);
  float L = 0.0f;
  float4 o = make_float4(0.f, 0.f, 0.f, 0.f);
  for (int s = 0; s < nsplit; ++s) {
    float wgt = __expf(pm[(size_t)s * BS + gr] - M);
    L += pl[(size_t)s * BS + gr] * wgt;
    float4 p = *(const float4*)(pacc + ((size_t)s * BS + gr) * Hn + dq);
    o.x += p.x * wgt; o.y += p.y * wgt; o.z += p.z * wgt; o.w += p.w * wgt;
  }
  float inv = 1.0f / L;
  float4 r = make_float4(o.x * inv, o.y * inv, o.z * inv, o.w * inv);
  *(float4*)(out + (size_t)gr * Hn + dq) = r;
}

extern "C" void kernel_launch(void* const* d_in, const int* in_sizes, int n_in,
                              void* d_out, int out_size, void* d_ws, size_t ws_size,
                              hipStream_t stream) {
  const float* q  = (const float*)d_in[0];
  const float* k  = (const float*)d_in[1];
  const float* v  = (const float*)d_in[2];
  const float* Wq = (const float*)d_in[3];
  const float* bq = (const float*)d_in[4];
  const float* Wk = (const float*)d_in[5];
  const float* bk = (const float*)d_in[6];
  const float* Wv = (const float*)d_in[7];
  const float* bv = (const float*)d_in[8];
  float* out = (float*)d_out;

  unsigned short* Wt = (unsigned short*)d_ws;            // [3][64][768] bf16
  unsigned short* qi = Wt + 3 * Hn * Cn;                 // bf16, pre-scaled by 1/sqrt(C)
  unsigned short* ki = qi + (size_t)BS * Hn;
  unsigned short* vi = ki + (size_t)BS * Hn;
  float* pacc = (float*)(vi + (size_t)BS * Hn);

  const size_t base_bytes = (size_t)(3 * Hn * Cn + 3 * (size_t)BS * Hn) * 2;
  const size_t avail = (ws_size > base_bytes) ? ws_size - base_bytes : 0;

  int nsplit = 4;
  while (nsplit > 1 &&
         (size_t)nsplit * ((size_t)BS * Hn * 4 + 2 * (size_t)BS * 4) > avail)
    nsplit >>= 1;
  bool direct = ((size_t)nsplit * ((size_t)BS * Hn * 4 + 2 * (size_t)BS * 4) > avail);

  float* pm = pacc + (size_t)nsplit * BS * Hn;
  float* pl = pm + (size_t)nsplit * BS;

  wconv<<<dim3((3 * Cn * Hn) / 256), dim3(256), 0, stream>>>(Wq, Wk, Wv, Wt);
  proj<<<dim3(768), dim3(256), 0, stream>>>(q, k, v, bq, bk, bv, Wt, qi, ki, vi);
  if (direct) {
    attn<0><<<dim3(256), dim3(256), 0, stream>>>(qi, ki, vi, nullptr, nullptr, nullptr, out, 32);
  } else {
    attn<1><<<dim3(256 * nsplit), dim3(256), 0, stream>>>(qi, ki, vi, pacc, pm, pl, nullptr,
                                                          32 / nsplit);
    combine<<<dim3(BS * 16 / 256), dim3(256), 0, stream>>>(pacc, pm, pl, out, nsplit);
  }
}